// Round 4
// baseline (14814.247 us; speedup 1.0000x reference)
//
#include <hip/hip_runtime.h>
#include <stdint.h>

#define T_IN  128
#define T_OUT 50
#define NW    8                         // waves per block (512 threads)
#define RPW   32                        // batch rows per WAVE (one batch per lane-col)

typedef __bf16 bf16x8_t __attribute__((ext_vector_type(8)));
typedef float  f32x16_t __attribute__((ext_vector_type(16)));

#define LOG2E  1.4426950408889634f
#define LOG2E2 2.8853900817779268f

__device__ __forceinline__ float rcp_f(float x) { return __builtin_amdgcn_rcpf(x); }
__device__ __forceinline__ float ex2(float x)   { return __builtin_amdgcn_exp2f(x); }
__device__ __forceinline__ uint32_t pk(__bf16 a, __bf16 b) {
    return (uint32_t)__builtin_bit_cast(uint16_t, a) |
           ((uint32_t)__builtin_bit_cast(uint16_t, b) << 16);
}
#define MFMA32(A, B, C) __builtin_amdgcn_mfma_f32_32x32x16_bf16(A, B, C, 0, 0, 0)
#define ZERO16 (f32x16_t){0.f,0.f,0.f,0.f,0.f,0.f,0.f,0.f,0.f,0.f,0.f,0.f,0.f,0.f,0.f,0.f}

// ======================= TRANSPOSED-GATES FORMULATION =======================
// r3 post-mortem: per-step __syncthreads (h exchange between the hf wave pair
// through LDS) = the ~29% all-wave stall. Fix: swap MFMA operands.
//   D[gu][batch] = A[gu][u] * B[u][batch]:  A = weights (LDS, loop-invariant
//   bytes IDENTICAL to r3's sFrag — A/B lane layouts are symmetric), B = h.
// Now lane n = ONE batch; h lives in registers as next step's B-frags:
// NO LDS h buffer, NO ds h traffic, NO barriers in the time loops. Each wave
// independently owns 32 batches -> 256 rows/block, grid=512 = exactly 2
// blocks/CU, one residency round, no tail.
//
// Unit bookkeeping (verified slot-by-slot):
//   B-frag f (u = f*16 + kg*8 + 2q + {0,1}), kg = lane>>5:
//     kg=0 needs u mod 16 in {0..7}; kg=1 needs {8..15}.
//   Activation D rows r = (j&3)+8*(j>>2)+4*kh produce, per lane-half kh,
//   pairs pr[hf][jp] at u = 32hf + 8*(jp>>1) + 2*(jp&1) + 4kh
//     kh=0: u mod 16 in {0,2,8,10}(+1); kh=1: {4,6,12,14}(+1)
//   -> half the pairs must swap across the kh halves: __shfl_xor(...,32).
//   Mapping (b = f&1, q in {0,1}):
//     kh=0: HF[f].u[q]=own pr[hf][4b+q];  HF[f].u[2+q]=partner pr[hf][4b+q]
//     kh=1: HF[f].u[q]=partner pr[hf][4b+2+q]; HF[f].u[2+q]=own pr[hf][4b+2+q]
//   -> per (f,q): send = kh ? pr[4b+q] : pr[4b+2+q]; recv = shfl_xor(send,32).
//
// Register budget: HF 16 + cs 32 + pr 16 + igp 16 + two acc chains 32 + misc
// ~15 with HF dead before pr completes -> peak ~120-125 <= 128 total under
// (512,4). Spill tripwire: FETCH >> 1 GB.  x is lane-local (no sXw ring);
// decoder feedback p0,p1 computed by the owning lane (no sXfb, no writer lane).

union HFu { bf16x8_t v; uint32_t u[4]; };

__device__ __forceinline__ void lstm_step(
    uint32_t xpack, uint32_t kmask, int kh,
    const uint8_t* __restrict__ fragT,   // sFrag + lane*16  (A = weights)
    const uint8_t* __restrict__ b2l,     // sB2  + lane*16  (A = Wih/bias)
    HFu (&HF)[4], float (&cs)[32])
{
    HFu ux;                              // B = x/bias rows (k=0,1,2 on kg=0)
    ux.u[0] = xpack & kmask;
    ux.u[1] = 0x00003F80u & kmask;       // 1.0 bias row
    ux.u[2] = 0u; ux.u[3] = 0u;

    uint32_t pr[2][8];

#define CHAIN(t, dst)                                                       \
    { const uint8_t* bp = fragT + (t) * 4096;                               \
      f32x16_t z = MFMA32(*(const bf16x8_t*)(bp),        HF[0].v, ZERO16);  \
      z = MFMA32(*(const bf16x8_t*)(bp + 1024), HF[1].v, z);                \
      z = MFMA32(*(const bf16x8_t*)(bp + 2048), HF[2].v, z);                \
      z = MFMA32(*(const bf16x8_t*)(bp + 3072), HF[3].v, z);                \
      dst = MFMA32(*(const bf16x8_t*)(b2l + (t) * 1024), ux.v, z); }

    #pragma unroll
    for (int hf = 0; hf < 2; ++hf) {
        // pass 1: gates i (t=hf*4+0), g (t=hf*4+2) -> igp = i*g
        f32x16_t ai, ag;
        CHAIN(hf * 4 + 0, ai)
        CHAIN(hf * 4 + 2, ag)
        float igp[16];
        #pragma unroll
        for (int j = 0; j < 16; ++j) {
            float ea = ex2(-ai[j]);      // weights pre-scaled -> bare exp2
            float eg = ex2(-ag[j]);      // g pre-scaled by 2*log2e
            igp[j] = (1.f - eg) * rcp_f((1.f + ea) * (1.f + eg));
        }
        // pass 2: gates f (1), o (3) -> c, h
        f32x16_t af, ao;
        CHAIN(hf * 4 + 1, af)
        CHAIN(hf * 4 + 3, ao)
        #pragma unroll
        for (int jp = 0; jp < 8; ++jp) {
            const int j0 = 2 * jp, j1 = j0 + 1;
            float og[2], ec[2];
            #pragma unroll
            for (int jj = 0; jj < 2; ++jj) {
                const int j = j0 + jj;
                float ef = ex2(-af[j]);
                float eo = ex2(-ao[j]);
                float pf_ = 1.f + ef, po = 1.f + eo;
                float rr = rcp_f(pf_ * po);
                float fgt = rr * po;     // sigmoid(f)
                og[jj]    = rr * pf_;    // sigmoid(o)
                float cn  = fgt * cs[hf * 16 + j] + igp[j];
                cs[hf * 16 + j] = cn;
                float y = fminf(fmaxf(cn * LOG2E2, -43.f), 43.f);
                ec[jj] = ex2(-y);
            }
            float C0 = 1.f + ec[0], C1 = 1.f + ec[1];
            float r2 = rcp_f(C0 * C1);
            float h0 = og[0] * (1.f - ec[0]) * r2 * C1;
            float h1 = og[1] * (1.f - ec[1]) * r2 * C0;
            pr[hf][jp] = pk((__bf16)h0, (__bf16)h1);
        }
    }
#undef CHAIN
    // ---- half-wave unit exchange: pr -> new h B-frags (HF dead above) ----
    #pragma unroll
    for (int f = 0; f < 4; ++f) {
        const int hfi = f >> 1, b4 = (f & 1) * 4;
        #pragma unroll
        for (int qq = 0; qq < 2; ++qq) {
            uint32_t lo = pr[hfi][b4 + qq];
            uint32_t hi = pr[hfi][b4 + 2 + qq];
            uint32_t send = kh ? lo : hi;
            uint32_t recv = __shfl_xor(send, 32, 64);
            HF[f].u[qq]     = kh ? recv : lo;
            HF[f].u[2 + qq] = kh ? hi   : recv;
        }
    }
}

__global__ __launch_bounds__(512, 4) void seq2seq_lstm(
    const float* __restrict__ in_seq,
    const float* __restrict__ WihE, const float* __restrict__ WhhE,
    const float* __restrict__ bihE, const float* __restrict__ bhhE,
    const float* __restrict__ WihD, const float* __restrict__ WhhD,
    const float* __restrict__ bihD, const float* __restrict__ bhhD,
    const float* __restrict__ Wfc,  const float* __restrict__ bfc,
    float* __restrict__ out)
{
    __shared__ __align__(16) uint8_t sFrag[32768];   // 8 tiles x 4 kfrags x 1KB
    __shared__ __align__(16) uint8_t sB2[8192];      // 8 tiles x 64 lanes x 16B
    __shared__ __align__(16) uint8_t sWfc[4096];     // FC A-frags, 4 kfrags x 1KB
    // total 45056 B; occupancy gated by regs (<=128 total) -> 16 waves/CU

    const int tid  = threadIdx.x;
    const int lane = tid & 63;
    const int wave = tid >> 6;
    const int m    = lane & 31;          // batch within wave
    const int kh   = lane >> 5;
    const uint32_t kmask = kh ? 0u : 0xFFFFFFFFu;

    auto stage_frags = [&](const float* Whh, const float* Wih,
                           const float* bih, const float* bhh) {
        // sFrag: BYTES IDENTICAL to r3 (A/B frag lane layouts symmetric)
        #pragma unroll 1
        for (int it = 0; it < 4; ++it) {
            int idx = it * 512 + tid;    // frag(0..31) x lane(0..63)
            int ln  = idx & 63;
            int fg  = idx >> 6;
            int kk  = fg & 3;
            int t   = fg >> 2;
            int g   = t & 3;
            int hfb = t >> 2;
            int gu  = (ln & 31);
            int kg  = ln >> 5;
            float sc = (g == 2) ? LOG2E2 : LOG2E;
            const float* wr = Whh + (g * 64 + hfb * 32 + gu) * 64 + kk * 16 + kg * 8;
            uint32_t wv[4];
            #pragma unroll
            for (int jj = 0; jj < 4; ++jj)
                wv[jj] = pk((__bf16)(sc * wr[2 * jj]), (__bf16)(sc * wr[2 * jj + 1]));
            uint32_t* d = (uint32_t*)(sFrag + t * 4096 + kk * 1024 + ln * 16);
            d[0] = wv[0]; d[1] = wv[1]; d[2] = wv[2]; d[3] = wv[3];
        }
        // sB2: full 64-lane layout, zeros pre-stored for kg=1 -> no masking
        {
            int ln = tid & 63;
            int t  = tid >> 6;           // 0..7 (512 threads cover all slots)
            int g  = t & 3;
            int hfb = t >> 2;
            uint32_t u0 = 0u, u1 = 0u;
            if (ln < 32) {
                float sc = (g == 2) ? LOG2E2 : LOG2E;
                int gu = g * 64 + hfb * 32 + ln;
                u0 = pk((__bf16)(sc * Wih[gu * 2 + 0]), (__bf16)(sc * Wih[gu * 2 + 1]));
                u1 = pk((__bf16)(sc * (bih[gu] + bhh[gu])), (__bf16)0.0f);
            }
            uint32_t* d = (uint32_t*)(sB2 + t * 1024 + ln * 16);
            d[0] = u0; d[1] = u1; d[2] = 0u; d[3] = 0u;
        }
    };

    stage_frags(WhhE, WihE, bihE, bhhE);
    __syncthreads();

    const int rowBase = blockIdx.x * (NW * RPW) + wave * RPW;
    const uint8_t* fragT = sFrag + lane * 16;
    const uint8_t* b2l   = sB2 + lane * 16;

    HFu HF[4];
    #pragma unroll
    for (int f = 0; f < 4; ++f) { HF[f].u[0] = HF[f].u[1] = HF[f].u[2] = HF[f].u[3] = 0u; }
    float cs[32];
    #pragma unroll
    for (int j = 0; j < 32; ++j) cs[j] = 0.f;

    // ================= encoder: x is lane-local, no LDS staging =================
    const float* gsrc = in_seq + (size_t)(rowBase + m) * (T_IN * 2);
    float4 pf = *(const float4*)gsrc;                 // steps t, t+1
    #pragma unroll 1
    for (int t = 0; t < T_IN; ++t) {
        uint32_t xa = (t & 1) ? pk((__bf16)pf.z, (__bf16)pf.w)
                              : pk((__bf16)pf.x, (__bf16)pf.y);
        if ((t & 1) && t < T_IN - 1)                  // refill for t+1, t+2
            pf = *(const float4*)(gsrc + (t + 1) * 2);
        lstm_step(xa, kmask, kh, fragT, b2l, HF, cs);
    }

    // ============ switch to decoder weights ============
    __syncthreads();                                  // all waves done with enc sFrag
    stage_frags(WhhD, WihD, bihD, bhhD);
    if (tid < 256) {                                  // FC A-frags: rows 0,1 = Wfc
        int f  = tid >> 6, ln = tid & 63;
        int kg = ln >> 5,  mm = ln & 31;
        const float* wr = Wfc + (mm & 1) * 64 + f * 16 + kg * 8;  // dup rows >=2
        uint32_t w[4];
        #pragma unroll
        for (int jj = 0; jj < 4; ++jj)
            w[jj] = pk((__bf16)wr[2 * jj], (__bf16)wr[2 * jj + 1]);
        uint32_t* d = (uint32_t*)(sWfc + f * 1024 + ln * 16);
        d[0] = w[0]; d[1] = w[1]; d[2] = w[2]; d[3] = w[3];
    }
    __syncthreads();

    uint32_t xpack = pk((__bf16)pf.z, (__bf16)pf.w);  // input_seq[:, -1]
    const float nb0 = -LOG2E * bfc[0], nb1 = -LOG2E * bfc[1];
    const uint8_t* wfcT = sWfc + lane * 16;

    // ================= decoder: barrier-free =================
    #pragma unroll 1
    for (int td = 0; td < T_OUT; ++td) {
        lstm_step(xpack, kmask, kh, fragT, b2l, HF, cs);
        // FC via MFMA on the NEW h frags: D rows 0,1 (kh=0, j=0,1) = logits
        f32x16_t pc = MFMA32(*(const bf16x8_t*)(wfcT),        HF[0].v, ZERO16);
        pc = MFMA32(*(const bf16x8_t*)(wfcT + 1024), HF[1].v, pc);
        pc = MFMA32(*(const bf16x8_t*)(wfcT + 2048), HF[2].v, pc);
        pc = MFMA32(*(const bf16x8_t*)(wfcT + 3072), HF[3].v, pc);
        if (kh == 0) {                                // lane owns batch m
            float p0 = rcp_f(1.f + ex2(__builtin_fmaf(-LOG2E, pc[0], nb0)));
            float p1 = rcp_f(1.f + ex2(__builtin_fmaf(-LOG2E, pc[1], nb1)));
            *(float2*)(out + ((size_t)(rowBase + m) * T_OUT + td) * 2)
                = make_float2(p0, p1);
            xpack = pk((__bf16)p0, (__bf16)p1);       // in-register feedback
        }
        // kh=1 lanes keep stale xpack: masked by kmask, never consumed
    }
}

extern "C" void kernel_launch(void* const* d_in, const int* in_sizes, int n_in,
                              void* d_out, int out_size, void* d_ws, size_t ws_size,
                              hipStream_t stream) {
    const float* in_seq = (const float*)d_in[0];
    const float* WihE = (const float*)d_in[1];
    const float* WhhE = (const float*)d_in[2];
    const float* bihE = (const float*)d_in[3];
    const float* bhhE = (const float*)d_in[4];
    const float* WihD = (const float*)d_in[5];
    const float* WhhD = (const float*)d_in[6];
    const float* bihD = (const float*)d_in[7];
    const float* bhhD = (const float*)d_in[8];
    const float* Wfc  = (const float*)d_in[9];
    const float* bfcp = (const float*)d_in[10];
    float* out = (float*)d_out;

    const int B = in_sizes[0] / (T_IN * 2);          // 131072
    dim3 grid(B / (NW * RPW)), block(NW * 64);       // 256 rows/block, 512 thr
    hipLaunchKernelGGL(seq2seq_lstm, grid, block, 0, stream,
                       in_seq, WihE, WhhE, bihE, bhhE,
                       WihD, WhhD, bihD, bhhD, Wfc, bfcp, out);
}

// Round 5
// 7529.334 us; speedup vs baseline: 1.9675x; 1.9675x over previous
//
#include <hip/hip_runtime.h>
#include <stdint.h>

#define T_IN  128
#define T_OUT 50
#define NW    8                         // waves per block (512 threads)
#define RPW   32                        // batch rows per WAVE (one batch per lane-col)

typedef __bf16 bf16x8_t __attribute__((ext_vector_type(8)));
typedef float  f32x16_t __attribute__((ext_vector_type(16)));

#define LOG2E  1.4426950408889634f
#define LOG2E2 2.8853900817779268f

__device__ __forceinline__ float rcp_f(float x) { return __builtin_amdgcn_rcpf(x); }
__device__ __forceinline__ float ex2(float x)   { return __builtin_amdgcn_exp2f(x); }
__device__ __forceinline__ uint32_t pk(__bf16 a, __bf16 b) {
    return (uint32_t)__builtin_bit_cast(uint16_t, a) |
           ((uint32_t)__builtin_bit_cast(uint16_t, b) << 16);
}
#define MFMA32(A, B, C) __builtin_amdgcn_mfma_f32_32x32x16_bf16(A, B, C, 0, 0, 0)
#define ZERO16 (f32x16_t){0.f,0.f,0.f,0.f,0.f,0.f,0.f,0.f,0.f,0.f,0.f,0.f,0.f,0.f,0.f,0.f}

// ======================= TRANSPOSED-GATES FORMULATION =======================
// (r4: formulation CORRECT — passed with identical absmax — but spilled: paired
// gate accumulators (32 transient) + load hoisting pushed peak past the 128-
// total cap; arch VGPR squeezed to 64, 50 GB scratch traffic, 14.8 ms.)
// r5 FIX: sequential gate chains g->i->f->o per hf, ONE f32x16 acc live at a
// time, result folded into a single 16-reg temp (tg -> igp -> th -> pr).
// rcp count kept identical by sharing each rcp across j-PAIRS instead of
// across gates: rr = rcp(p_j0*p_j1); recover both via 2 muls.
// sched_barrier(0) before each chain stops cross-chain load hoisting (the r4
// register blow-up). Peak live ~100-116 <= 128 total under (512,4).
//
// Unit bookkeeping (HW-verified by r4 passing):
//   B-frag f (u = f*16 + kg*8 + 2q + {0,1}), kg = lane>>5.
//   Activation rows r = (j&3)+8*(j>>2)+4*kh -> pairs pr[hf][jp] at
//   u = 32hf + 8*(jp>>1) + 2*(jp&1) + 4kh; half the pairs swap across kh
//   halves via __shfl_xor(..,32):
//     per (f,q): send = kh ? pr[4b+q] : pr[4b+2+q]; recv = shfl_xor(send,32);
//     kh=0: {own lo, recv}; kh=1: {recv, own hi}.
// Spill tripwire: FETCH >> 1 GB -> fall back to __launch_bounds__(512,3).

union HFu { bf16x8_t v; uint32_t u[4]; };

__device__ __forceinline__ void lstm_step(
    uint32_t xpack, uint32_t kmask, int kh,
    const uint8_t* __restrict__ fragT,   // sFrag + lane*16  (A = weights)
    const uint8_t* __restrict__ b2l,     // sB2  + lane*16  (A = Wih/bias)
    HFu (&HF)[4], float (&cs)[32])
{
    HFu ux;                              // B = x/bias rows (k=0,1,2 on kg=0)
    ux.u[0] = xpack & kmask;
    ux.u[1] = 0x00003F80u & kmask;       // 1.0 bias row
    ux.u[2] = 0u; ux.u[3] = 0u;

    uint32_t pr[2][8];

#define CHAIN(t, dst)                                                       \
    { __builtin_amdgcn_sched_barrier(0);                                    \
      const uint8_t* bp = fragT + (t) * 4096;                               \
      f32x16_t z = MFMA32(*(const bf16x8_t*)(bp),        HF[0].v, ZERO16);  \
      z = MFMA32(*(const bf16x8_t*)(bp + 1024), HF[1].v, z);                \
      z = MFMA32(*(const bf16x8_t*)(bp + 2048), HF[2].v, z);                \
      z = MFMA32(*(const bf16x8_t*)(bp + 3072), HF[3].v, z);                \
      dst = MFMA32(*(const bf16x8_t*)(b2l + (t) * 1024), ux.v, z); }

    #pragma unroll
    for (int hf = 0; hf < 2; ++hf) {
        f32x16_t acc;
        float tmp[16];                   // tg -> igp -> th (sequential reuse)

        // ---- gate g: tmp = tanh-part = (1-eg)/(1+eg) ----
        CHAIN(hf * 4 + 2, acc)
        #pragma unroll
        for (int jp = 0; jp < 8; ++jp) {
            const int j0 = 2 * jp, j1 = j0 + 1;
            float e0 = ex2(-acc[j0]), e1 = ex2(-acc[j1]);   // pre-scaled 2log2e
            float p0 = 1.f + e0, p1 = 1.f + e1;
            float rr = rcp_f(p0 * p1);
            tmp[j0] = (1.f - e0) * (rr * p1);
            tmp[j1] = (1.f - e1) * (rr * p0);
        }
        // ---- gate i: tmp = igp = sigmoid(i) * tanh(g) ----
        CHAIN(hf * 4 + 0, acc)
        #pragma unroll
        for (int jp = 0; jp < 8; ++jp) {
            const int j0 = 2 * jp, j1 = j0 + 1;
            float e0 = ex2(-acc[j0]), e1 = ex2(-acc[j1]);
            float p0 = 1.f + e0, p1 = 1.f + e1;
            float rr = rcp_f(p0 * p1);
            tmp[j0] *= (rr * p1);
            tmp[j1] *= (rr * p0);
        }
        // ---- gate f: c update; tmp = th = tanh(c) ----
        CHAIN(hf * 4 + 1, acc)
        #pragma unroll
        for (int jp = 0; jp < 8; ++jp) {
            const int j0 = 2 * jp, j1 = j0 + 1;
            float e0 = ex2(-acc[j0]), e1 = ex2(-acc[j1]);
            float p0 = 1.f + e0, p1 = 1.f + e1;
            float rr = rcp_f(p0 * p1);
            float cn0 = (rr * p1) * cs[hf * 16 + j0] + tmp[j0];
            float cn1 = (rr * p0) * cs[hf * 16 + j1] + tmp[j1];
            cs[hf * 16 + j0] = cn0;
            cs[hf * 16 + j1] = cn1;
            float y0 = fminf(fmaxf(cn0 * LOG2E2, -43.f), 43.f);
            float y1 = fminf(fmaxf(cn1 * LOG2E2, -43.f), 43.f);
            float ec0 = ex2(-y0), ec1 = ex2(-y1);
            float C0 = 1.f + ec0, C1 = 1.f + ec1;
            float r2 = rcp_f(C0 * C1);
            tmp[j0] = (1.f - ec0) * (r2 * C1);
            tmp[j1] = (1.f - ec1) * (r2 * C0);
        }
        // ---- gate o: h = sigmoid(o) * th; pack ----
        CHAIN(hf * 4 + 3, acc)
        #pragma unroll
        for (int jp = 0; jp < 8; ++jp) {
            const int j0 = 2 * jp, j1 = j0 + 1;
            float e0 = ex2(-acc[j0]), e1 = ex2(-acc[j1]);
            float p0 = 1.f + e0, p1 = 1.f + e1;
            float rr = rcp_f(p0 * p1);
            float h0 = tmp[j0] * (rr * p1);
            float h1 = tmp[j1] * (rr * p0);
            pr[hf][jp] = pk((__bf16)h0, (__bf16)h1);
        }
    }
#undef CHAIN
    // ---- half-wave unit exchange: pr -> new h B-frags ----
    #pragma unroll
    for (int f = 0; f < 4; ++f) {
        const int hfi = f >> 1, b4 = (f & 1) * 4;
        #pragma unroll
        for (int qq = 0; qq < 2; ++qq) {
            uint32_t lo = pr[hfi][b4 + qq];
            uint32_t hi = pr[hfi][b4 + 2 + qq];
            uint32_t send = kh ? lo : hi;
            uint32_t recv = __shfl_xor(send, 32, 64);
            HF[f].u[qq]     = kh ? recv : lo;
            HF[f].u[2 + qq] = kh ? hi   : recv;
        }
    }
}

__global__ __launch_bounds__(512, 4) void seq2seq_lstm(
    const float* __restrict__ in_seq,
    const float* __restrict__ WihE, const float* __restrict__ WhhE,
    const float* __restrict__ bihE, const float* __restrict__ bhhE,
    const float* __restrict__ WihD, const float* __restrict__ WhhD,
    const float* __restrict__ bihD, const float* __restrict__ bhhD,
    const float* __restrict__ Wfc,  const float* __restrict__ bfc,
    float* __restrict__ out)
{
    __shared__ __align__(16) uint8_t sFrag[32768];   // 8 tiles x 4 kfrags x 1KB
    __shared__ __align__(16) uint8_t sB2[8192];      // 8 tiles x 64 lanes x 16B
    __shared__ __align__(16) uint8_t sWfc[4096];     // FC A-frags, 4 kfrags x 1KB
    // total 45056 B; occupancy gated by regs (<=128 total) -> 16 waves/CU

    const int tid  = threadIdx.x;
    const int lane = tid & 63;
    const int wave = tid >> 6;
    const int m    = lane & 31;          // batch within wave
    const int kh   = lane >> 5;
    const uint32_t kmask = kh ? 0u : 0xFFFFFFFFu;

    auto stage_frags = [&](const float* Whh, const float* Wih,
                           const float* bih, const float* bhh) {
        #pragma unroll 1
        for (int it = 0; it < 4; ++it) {
            int idx = it * 512 + tid;    // frag(0..31) x lane(0..63)
            int ln  = idx & 63;
            int fg  = idx >> 6;
            int kk  = fg & 3;
            int t   = fg >> 2;
            int g   = t & 3;
            int hfb = t >> 2;
            int gu  = (ln & 31);
            int kg  = ln >> 5;
            float sc = (g == 2) ? LOG2E2 : LOG2E;
            const float* wr = Whh + (g * 64 + hfb * 32 + gu) * 64 + kk * 16 + kg * 8;
            uint32_t wv[4];
            #pragma unroll
            for (int jj = 0; jj < 4; ++jj)
                wv[jj] = pk((__bf16)(sc * wr[2 * jj]), (__bf16)(sc * wr[2 * jj + 1]));
            uint32_t* d = (uint32_t*)(sFrag + t * 4096 + kk * 1024 + ln * 16);
            d[0] = wv[0]; d[1] = wv[1]; d[2] = wv[2]; d[3] = wv[3];
        }
        // sB2: full 64-lane layout, zeros pre-stored for kg=1
        {
            int ln = tid & 63;
            int t  = tid >> 6;           // 0..7
            int g  = t & 3;
            int hfb = t >> 2;
            uint32_t u0 = 0u, u1 = 0u;
            if (ln < 32) {
                float sc = (g == 2) ? LOG2E2 : LOG2E;
                int gu = g * 64 + hfb * 32 + ln;
                u0 = pk((__bf16)(sc * Wih[gu * 2 + 0]), (__bf16)(sc * Wih[gu * 2 + 1]));
                u1 = pk((__bf16)(sc * (bih[gu] + bhh[gu])), (__bf16)0.0f);
            }
            uint32_t* d = (uint32_t*)(sB2 + t * 1024 + ln * 16);
            d[0] = u0; d[1] = u1; d[2] = 0u; d[3] = 0u;
        }
    };

    stage_frags(WhhE, WihE, bihE, bhhE);
    __syncthreads();

    const int rowBase = blockIdx.x * (NW * RPW) + wave * RPW;
    const uint8_t* fragT = sFrag + lane * 16;
    const uint8_t* b2l   = sB2 + lane * 16;

    HFu HF[4];
    #pragma unroll
    for (int f = 0; f < 4; ++f) { HF[f].u[0] = HF[f].u[1] = HF[f].u[2] = HF[f].u[3] = 0u; }
    float cs[32];
    #pragma unroll
    for (int j = 0; j < 32; ++j) cs[j] = 0.f;

    // ================= encoder: x is lane-local, no LDS staging =================
    const float* gsrc = in_seq + (size_t)(rowBase + m) * (T_IN * 2);
    float4 pf = *(const float4*)gsrc;                 // steps t, t+1
    #pragma unroll 1
    for (int t = 0; t < T_IN; ++t) {
        uint32_t xa = (t & 1) ? pk((__bf16)pf.z, (__bf16)pf.w)
                              : pk((__bf16)pf.x, (__bf16)pf.y);
        if ((t & 1) && t < T_IN - 1)                  // refill for t+1, t+2
            pf = *(const float4*)(gsrc + (t + 1) * 2);
        lstm_step(xa, kmask, kh, fragT, b2l, HF, cs);
    }

    // ============ switch to decoder weights ============
    __syncthreads();                                  // all waves done with enc sFrag
    stage_frags(WhhD, WihD, bihD, bhhD);
    if (tid < 256) {                                  // FC A-frags: rows 0,1 = Wfc
        int f  = tid >> 6, ln = tid & 63;
        int kg = ln >> 5,  mm = ln & 31;
        const float* wr = Wfc + (mm & 1) * 64 + f * 16 + kg * 8;  // dup rows >=2
        uint32_t w[4];
        #pragma unroll
        for (int jj = 0; jj < 4; ++jj)
            w[jj] = pk((__bf16)wr[2 * jj], (__bf16)wr[2 * jj + 1]);
        uint32_t* d = (uint32_t*)(sWfc + f * 1024 + ln * 16);
        d[0] = w[0]; d[1] = w[1]; d[2] = w[2]; d[3] = w[3];
    }
    __syncthreads();

    uint32_t xpack = pk((__bf16)pf.z, (__bf16)pf.w);  // input_seq[:, -1]
    const float nb0 = -LOG2E * bfc[0], nb1 = -LOG2E * bfc[1];
    const uint8_t* wfcT = sWfc + lane * 16;

    // ================= decoder: barrier-free =================
    #pragma unroll 1
    for (int td = 0; td < T_OUT; ++td) {
        lstm_step(xpack, kmask, kh, fragT, b2l, HF, cs);
        // FC via MFMA on the NEW h frags: D rows 0,1 (kh=0, j=0,1) = logits
        f32x16_t pc = MFMA32(*(const bf16x8_t*)(wfcT),        HF[0].v, ZERO16);
        pc = MFMA32(*(const bf16x8_t*)(wfcT + 1024), HF[1].v, pc);
        pc = MFMA32(*(const bf16x8_t*)(wfcT + 2048), HF[2].v, pc);
        pc = MFMA32(*(const bf16x8_t*)(wfcT + 3072), HF[3].v, pc);
        if (kh == 0) {                                // lane owns batch m
            float p0 = rcp_f(1.f + ex2(__builtin_fmaf(-LOG2E, pc[0], nb0)));
            float p1 = rcp_f(1.f + ex2(__builtin_fmaf(-LOG2E, pc[1], nb1)));
            *(float2*)(out + ((size_t)(rowBase + m) * T_OUT + td) * 2)
                = make_float2(p0, p1);
            xpack = pk((__bf16)p0, (__bf16)p1);       // in-register feedback
        }
        // kh=1 lanes keep stale xpack: masked by kmask, never consumed
    }
}

extern "C" void kernel_launch(void* const* d_in, const int* in_sizes, int n_in,
                              void* d_out, int out_size, void* d_ws, size_t ws_size,
                              hipStream_t stream) {
    const float* in_seq = (const float*)d_in[0];
    const float* WihE = (const float*)d_in[1];
    const float* WhhE = (const float*)d_in[2];
    const float* bihE = (const float*)d_in[3];
    const float* bhhE = (const float*)d_in[4];
    const float* WihD = (const float*)d_in[5];
    const float* WhhD = (const float*)d_in[6];
    const float* bihD = (const float*)d_in[7];
    const float* bhhD = (const float*)d_in[8];
    const float* Wfc  = (const float*)d_in[9];
    const float* bfcp = (const float*)d_in[10];
    float* out = (float*)d_out;

    const int B = in_sizes[0] / (T_IN * 2);          // 131072
    dim3 grid(B / (NW * RPW)), block(NW * 64);       // 256 rows/block, 512 thr
    hipLaunchKernelGGL(seq2seq_lstm, grid, block, 0, stream,
                       in_seq, WihE, WhhE, bihE, bhhE,
                       WihD, WhhD, bihD, bhhD, Wfc, bfcp, out);
}

// Round 7
// 4327.188 us; speedup vs baseline: 3.4235x; 1.7400x over previous
//
#include <hip/hip_runtime.h>
#include <stdint.h>

#define T_IN  128
#define T_OUT 50
#define NW    4                         // waves per block (256 threads)
#define RPW   32                        // batch rows per WAVE (one batch per lane-col)

typedef __bf16 bf16x8_t __attribute__((ext_vector_type(8)));
typedef float  f32x16_t __attribute__((ext_vector_type(16)));

#define LOG2E  1.4426950408889634f
#define LOG2E2 2.8853900817779268f

__device__ __forceinline__ float rcp_f(float x) { return __builtin_amdgcn_rcpf(x); }
__device__ __forceinline__ float ex2(float x)   { return __builtin_amdgcn_exp2f(x); }
__device__ __forceinline__ uint32_t pk(__bf16 a, __bf16 b) {
    return (uint32_t)__builtin_bit_cast(uint16_t, a) |
           ((uint32_t)__builtin_bit_cast(uint16_t, b) << 16);
}
#define MFMA32(A, B, C) __builtin_amdgcn_mfma_f32_32x32x16_bf16(A, B, C, 0, 0, 0)
#define ZERO16 (f32x16_t){0.f,0.f,0.f,0.f,0.f,0.f,0.f,0.f,0.f,0.f,0.f,0.f,0.f,0.f,0.f,0.f}

// ======================= TRANSPOSED-GATES FORMULATION =======================
// r4: formulation CORRECT but paired gate accs spilled (50 GB scratch).
// r5: sequential chains halved spill (18 GB); peak-live ~132 > 128-total cap
//     (4 waves/EU). r6 (SGB pacing, unbenched) -> container failure.
// r7: DON'T squeeze under 128 — raise the cap. __launch_bounds__(256,3):
//     cap ~170 >> 132 natural peak -> guaranteed no spill. NW=4 so block
//     granularity matches 12 waves/CU: 3 blocks x 4 waves = 3 waves/SIMD.
//     (8-wave blocks would leave only 8 waves/CU resident at this cap.)
//     Grid 1024, 768 resident -> 1.33 residency rounds (accepted tail).
// Regime arithmetic: 240 trans/step/wave x 8cyc = 1920 cyc; 3 waves x 178
// steps ~ 427 us/SIMD trans-pipe floor -> expect ~0.9-1.6 ms total.
//
// Unit bookkeeping (HW-verified by r4/r5 passing):
//   B-frag f (u = f*16 + kg*8 + 2q + {0,1}), kg = lane>>5.
//   Activation rows r = (j&3)+8*(j>>2)+4*kh -> pairs pr[hf][jp] at
//   u = 32hf + 8*(jp>>1) + 2*(jp&1) + 4kh; half the pairs swap across kh
//   halves via __shfl_xor(..,32):
//     per (f,q): send = kh ? pr[4b+q] : pr[4b+2+q]; recv = shfl_xor(send,32);
//     kh=0: {own lo, recv}; kh=1: {recv, own hi}.
// Spill tripwire: FETCH >> 1 GB -> formulation's register floor too high.

union HFu { bf16x8_t v; uint32_t u[4]; };

__device__ __forceinline__ void lstm_step(
    uint32_t xpack, uint32_t kmask, int kh,
    const uint8_t* __restrict__ fragT,   // sFrag + lane*16  (A = weights)
    const uint8_t* __restrict__ b2l,     // sB2  + lane*16  (A = Wih/bias)
    HFu (&HF)[4], float (&cs)[32])
{
    HFu ux;                              // B = x/bias rows (k=0,1,2 on kg=0)
    ux.u[0] = xpack & kmask;
    ux.u[1] = 0x00003F80u & kmask;       // 1.0 bias row
    ux.u[2] = 0u; ux.u[3] = 0u;

    uint32_t pr[2][8];

#define CHAIN(t, dst)                                                       \
    { __builtin_amdgcn_sched_barrier(0);                                    \
      const uint8_t* bp = fragT + (t) * 4096;                               \
      f32x16_t z = MFMA32(*(const bf16x8_t*)(bp),        HF[0].v, ZERO16);  \
      z = MFMA32(*(const bf16x8_t*)(bp + 1024), HF[1].v, z);                \
      z = MFMA32(*(const bf16x8_t*)(bp + 2048), HF[2].v, z);                \
      z = MFMA32(*(const bf16x8_t*)(bp + 3072), HF[3].v, z);                \
      dst = MFMA32(*(const bf16x8_t*)(b2l + (t) * 1024), ux.v, z); }

    #pragma unroll
    for (int hf = 0; hf < 2; ++hf) {
        f32x16_t acc;
        float tmp[16];                   // tg -> igp -> th (sequential reuse)

        // ---- gate g: tmp = tanh-part = (1-eg)/(1+eg) ----
        CHAIN(hf * 4 + 2, acc)
        #pragma unroll
        for (int jp = 0; jp < 8; ++jp) {
            const int j0 = 2 * jp, j1 = j0 + 1;
            float e0 = ex2(-acc[j0]), e1 = ex2(-acc[j1]);   // pre-scaled 2log2e
            float p0 = 1.f + e0, p1 = 1.f + e1;
            float rr = rcp_f(p0 * p1);
            tmp[j0] = (1.f - e0) * (rr * p1);
            tmp[j1] = (1.f - e1) * (rr * p0);
        }
        // ---- gate i: tmp = igp = sigmoid(i) * tanh(g) ----
        CHAIN(hf * 4 + 0, acc)
        #pragma unroll
        for (int jp = 0; jp < 8; ++jp) {
            const int j0 = 2 * jp, j1 = j0 + 1;
            float e0 = ex2(-acc[j0]), e1 = ex2(-acc[j1]);
            float p0 = 1.f + e0, p1 = 1.f + e1;
            float rr = rcp_f(p0 * p1);
            tmp[j0] *= (rr * p1);
            tmp[j1] *= (rr * p0);
        }
        // ---- gate f: c update; tmp = th = tanh(c) ----
        CHAIN(hf * 4 + 1, acc)
        #pragma unroll
        for (int jp = 0; jp < 8; ++jp) {
            const int j0 = 2 * jp, j1 = j0 + 1;
            float e0 = ex2(-acc[j0]), e1 = ex2(-acc[j1]);
            float p0 = 1.f + e0, p1 = 1.f + e1;
            float rr = rcp_f(p0 * p1);
            float cn0 = (rr * p1) * cs[hf * 16 + j0] + tmp[j0];
            float cn1 = (rr * p0) * cs[hf * 16 + j1] + tmp[j1];
            cs[hf * 16 + j0] = cn0;
            cs[hf * 16 + j1] = cn1;
            float y0 = fminf(fmaxf(cn0 * LOG2E2, -43.f), 43.f);
            float y1 = fminf(fmaxf(cn1 * LOG2E2, -43.f), 43.f);
            float ec0 = ex2(-y0), ec1 = ex2(-y1);
            float C0 = 1.f + ec0, C1 = 1.f + ec1;
            float r2 = rcp_f(C0 * C1);
            tmp[j0] = (1.f - ec0) * (r2 * C1);
            tmp[j1] = (1.f - ec1) * (r2 * C0);
        }
        // ---- gate o: h = sigmoid(o) * th; pack ----
        CHAIN(hf * 4 + 3, acc)
        #pragma unroll
        for (int jp = 0; jp < 8; ++jp) {
            const int j0 = 2 * jp, j1 = j0 + 1;
            float e0 = ex2(-acc[j0]), e1 = ex2(-acc[j1]);
            float p0 = 1.f + e0, p1 = 1.f + e1;
            float rr = rcp_f(p0 * p1);
            float h0 = tmp[j0] * (rr * p1);
            float h1 = tmp[j1] * (rr * p0);
            pr[hf][jp] = pk((__bf16)h0, (__bf16)h1);
        }
    }
#undef CHAIN
    // ---- half-wave unit exchange: pr -> new h B-frags ----
    #pragma unroll
    for (int f = 0; f < 4; ++f) {
        const int hfi = f >> 1, b4 = (f & 1) * 4;
        #pragma unroll
        for (int qq = 0; qq < 2; ++qq) {
            uint32_t lo = pr[hfi][b4 + qq];
            uint32_t hi = pr[hfi][b4 + 2 + qq];
            uint32_t send = kh ? lo : hi;
            uint32_t recv = __shfl_xor(send, 32, 64);
            HF[f].u[qq]     = kh ? recv : lo;
            HF[f].u[2 + qq] = kh ? hi   : recv;
        }
    }
}

__global__ __launch_bounds__(256, 3) void seq2seq_lstm(
    const float* __restrict__ in_seq,
    const float* __restrict__ WihE, const float* __restrict__ WhhE,
    const float* __restrict__ bihE, const float* __restrict__ bhhE,
    const float* __restrict__ WihD, const float* __restrict__ WhhD,
    const float* __restrict__ bihD, const float* __restrict__ bhhD,
    const float* __restrict__ Wfc,  const float* __restrict__ bfc,
    float* __restrict__ out)
{
    __shared__ __align__(16) uint8_t sFrag[32768];   // 8 tiles x 4 kfrags x 1KB
    __shared__ __align__(16) uint8_t sB2[8192];      // 8 tiles x 64 lanes x 16B
    __shared__ __align__(16) uint8_t sWfc[4096];     // FC A-frags, 4 kfrags x 1KB
    // total 45056 B -> 3 blocks/CU (12 waves = 3/SIMD) at reg cap ~170

    const int tid  = threadIdx.x;
    const int lane = tid & 63;
    const int wave = tid >> 6;
    const int m    = lane & 31;          // batch within wave
    const int kh   = lane >> 5;
    const uint32_t kmask = kh ? 0u : 0xFFFFFFFFu;

    auto stage_frags = [&](const float* Whh, const float* Wih,
                           const float* bih, const float* bhh) {
        #pragma unroll 1
        for (int it = 0; it < 8; ++it) {
            int idx = it * 256 + tid;    // frag(0..31) x lane(0..63)
            int ln  = idx & 63;
            int fg  = idx >> 6;
            int kk  = fg & 3;
            int t   = fg >> 2;
            int g   = t & 3;
            int hfb = t >> 2;
            int gu  = (ln & 31);
            int kg  = ln >> 5;
            float sc = (g == 2) ? LOG2E2 : LOG2E;
            const float* wr = Whh + (g * 64 + hfb * 32 + gu) * 64 + kk * 16 + kg * 8;
            uint32_t wv[4];
            #pragma unroll
            for (int jj = 0; jj < 4; ++jj)
                wv[jj] = pk((__bf16)(sc * wr[2 * jj]), (__bf16)(sc * wr[2 * jj + 1]));
            uint32_t* d = (uint32_t*)(sFrag + t * 4096 + kk * 1024 + ln * 16);
            d[0] = wv[0]; d[1] = wv[1]; d[2] = wv[2]; d[3] = wv[3];
        }
        // sB2: 8 tiles x 64 lanes; zeros pre-stored for kg=1
        #pragma unroll 1
        for (int it = 0; it < 2; ++it) {
            int idx = it * 256 + tid;    // 0..511 = tile(0..7) x lane(0..63)
            int ln  = idx & 63;
            int t   = idx >> 6;
            int g   = t & 3;
            int hfb = t >> 2;
            uint32_t u0 = 0u, u1 = 0u;
            if (ln < 32) {
                float sc = (g == 2) ? LOG2E2 : LOG2E;
                int gu = g * 64 + hfb * 32 + ln;
                u0 = pk((__bf16)(sc * Wih[gu * 2 + 0]), (__bf16)(sc * Wih[gu * 2 + 1]));
                u1 = pk((__bf16)(sc * (bih[gu] + bhh[gu])), (__bf16)0.0f);
            }
            uint32_t* d = (uint32_t*)(sB2 + t * 1024 + ln * 16);
            d[0] = u0; d[1] = u1; d[2] = 0u; d[3] = 0u;
        }
    };

    stage_frags(WhhE, WihE, bihE, bhhE);
    __syncthreads();

    const int rowBase = blockIdx.x * (NW * RPW) + wave * RPW;
    const uint8_t* fragT = sFrag + lane * 16;
    const uint8_t* b2l   = sB2 + lane * 16;

    HFu HF[4];
    #pragma unroll
    for (int f = 0; f < 4; ++f) { HF[f].u[0] = HF[f].u[1] = HF[f].u[2] = HF[f].u[3] = 0u; }
    float cs[32];
    #pragma unroll
    for (int j = 0; j < 32; ++j) cs[j] = 0.f;

    // ================= encoder: x is lane-local, no LDS staging =================
    const float* gsrc = in_seq + (size_t)(rowBase + m) * (T_IN * 2);
    float4 pf = *(const float4*)gsrc;                 // steps t, t+1
    #pragma unroll 1
    for (int t = 0; t < T_IN; ++t) {
        uint32_t xa = (t & 1) ? pk((__bf16)pf.z, (__bf16)pf.w)
                              : pk((__bf16)pf.x, (__bf16)pf.y);
        if ((t & 1) && t < T_IN - 1)                  // refill for t+1, t+2
            pf = *(const float4*)(gsrc + (t + 1) * 2);
        lstm_step(xa, kmask, kh, fragT, b2l, HF, cs);
    }

    // ============ switch to decoder weights ============
    __syncthreads();                                  // all waves done with enc sFrag
    stage_frags(WhhD, WihD, bihD, bhhD);
    {                                                 // FC A-frags: rows 0,1 = Wfc
        int f  = tid >> 6, ln = tid & 63;             // 256 threads = 4 frags exactly
        int kg = ln >> 5,  mm = ln & 31;
        const float* wr = Wfc + (mm & 1) * 64 + f * 16 + kg * 8;  // dup rows >=2
        uint32_t w[4];
        #pragma unroll
        for (int jj = 0; jj < 4; ++jj)
            w[jj] = pk((__bf16)wr[2 * jj], (__bf16)wr[2 * jj + 1]);
        uint32_t* d = (uint32_t*)(sWfc + f * 1024 + ln * 16);
        d[0] = w[0]; d[1] = w[1]; d[2] = w[2]; d[3] = w[3];
    }
    __syncthreads();

    uint32_t xpack = pk((__bf16)pf.z, (__bf16)pf.w);  // input_seq[:, -1]
    const float nb0 = -LOG2E * bfc[0], nb1 = -LOG2E * bfc[1];
    const uint8_t* wfcT = sWfc + lane * 16;

    // ================= decoder: barrier-free =================
    #pragma unroll 1
    for (int td = 0; td < T_OUT; ++td) {
        lstm_step(xpack, kmask, kh, fragT, b2l, HF, cs);
        // FC via MFMA on the NEW h frags: D rows 0,1 (kh=0, j=0,1) = logits
        __builtin_amdgcn_sched_barrier(0);
        f32x16_t pc = MFMA32(*(const bf16x8_t*)(wfcT),        HF[0].v, ZERO16);
        pc = MFMA32(*(const bf16x8_t*)(wfcT + 1024), HF[1].v, pc);
        pc = MFMA32(*(const bf16x8_t*)(wfcT + 2048), HF[2].v, pc);
        pc = MFMA32(*(const bf16x8_t*)(wfcT + 3072), HF[3].v, pc);
        if (kh == 0) {                                // lane owns batch m
            float p0 = rcp_f(1.f + ex2(__builtin_fmaf(-LOG2E, pc[0], nb0)));
            float p1 = rcp_f(1.f + ex2(__builtin_fmaf(-LOG2E, pc[1], nb1)));
            *(float2*)(out + ((size_t)(rowBase + m) * T_OUT + td) * 2)
                = make_float2(p0, p1);
            xpack = pk((__bf16)p0, (__bf16)p1);       // in-register feedback
        }
        // kh=1 lanes keep stale xpack: masked by kmask, never consumed
    }
}

extern "C" void kernel_launch(void* const* d_in, const int* in_sizes, int n_in,
                              void* d_out, int out_size, void* d_ws, size_t ws_size,
                              hipStream_t stream) {
    const float* in_seq = (const float*)d_in[0];
    const float* WihE = (const float*)d_in[1];
    const float* WhhE = (const float*)d_in[2];
    const float* bihE = (const float*)d_in[3];
    const float* bhhE = (const float*)d_in[4];
    const float* WihD = (const float*)d_in[5];
    const float* WhhD = (const float*)d_in[6];
    const float* bihD = (const float*)d_in[7];
    const float* bhhD = (const float*)d_in[8];
    const float* Wfc  = (const float*)d_in[9];
    const float* bfcp = (const float*)d_in[10];
    float* out = (float*)d_out;

    const int B = in_sizes[0] / (T_IN * 2);          // 131072
    dim3 grid(B / (NW * RPW)), block(NW * 64);       // 128 rows/block, 256 thr
    hipLaunchKernelGGL(seq2seq_lstm, grid, block, 0, stream,
                       in_seq, WihE, WhhE, bihE, bhhE,
                       WihD, WhhD, bihD, bhhD, Wfc, bfcp, out);
}

// Round 8
// 4293.599 us; speedup vs baseline: 3.4503x; 1.0078x over previous
//
#include <hip/hip_runtime.h>
#include <stdint.h>

#define T_IN  128
#define T_OUT 50
#define NW    4                         // waves per block (256 threads)
#define BPW   16                        // batches per wave (16x16 MFMA cols)

typedef __bf16 bf16x8_t __attribute__((ext_vector_type(8)));
typedef float  f32x4_t  __attribute__((ext_vector_type(4)));

#define LOG2E  1.4426950408889634f
#define LOG2E2 2.8853900817779268f

__device__ __forceinline__ float rcp_f(float x) { return __builtin_amdgcn_rcpf(x); }
__device__ __forceinline__ float ex2(float x)   { return __builtin_amdgcn_exp2f(x); }
__device__ __forceinline__ uint32_t pk(__bf16 a, __bf16 b) {
    return (uint32_t)__builtin_bit_cast(uint16_t, a) |
           ((uint32_t)__builtin_bit_cast(uint16_t, b) << 16);
}
#define MFMA16(A, B, C) __builtin_amdgcn_mfma_f32_16x16x32_bf16(A, B, C, 0, 0, 0)
#define ZERO4 (f32x4_t){0.f, 0.f, 0.f, 0.f}

// ============== 16x16 TRANSPOSED-GATES, EXCHANGE-FREE (r8) ==============
// REGISTER LESSON (r0-r7): this toolchain splits the unified VGPR file EVENLY
// between arch and AGPR when MFMA is present: arch budget = cap/2 (observed
// exactly in r0/r1/r3/r5/r7). The 32x32 transposed kernel's VALU-side ~110
// regs can never fit cap/2 at >=3 waves/SIMD -> permanent mild spill (r7).
// FIX 1 (tile shrink): 16x16x32 MFMA -> wave owns 16 batches; cs 16, HF 8,
//   acc f32x4, tmp 4 -> VALU-side ~70 <= 84 (=168/2 at (256,3)) -> no spill,
//   3 waves/SIMD, 12 waves/CU.
// FIX 2 (unit relabel): D-row->unit map is OUR choice via A-row staging.
//   u(s,m) = 8*(m>>2) + 4*(s&1) + (m&3) + 32*(s>>1)  (bijection [0..3]x[0..15]
//   -> [0..63]) makes lane q's produced units == its consumed B-slots:
//   HF0.u[i] = ph[i>>1][i&1]; HF1.u[i] = ph[2+(i>>1)][i&1]. ZERO shuffles.
//   B k-slot == unit identity -> Whh/Wfc K columns unpermuted.
// Layouts: C/D 16x16 (HW-verified m89/m91): col=lane&15, row=(lane>>4)*4+reg.
//   A: A[m=lane&15][k=(lane>>4)*8+j]; B symmetric (analogous to our
//   r0-r7-proven 32x32 pattern).
// Chains per tile (g,s): 2 W-frags (K=64 h) + 1 xb-frag (k'=0,1,2 = x0,x1,1).
// LDS/step: 32 ds_read_b128 + 16 ds_read_b64 -> ~760us pipe floor.
// Spill tripwire: FETCH > 2 GB -> fall back to __launch_bounds__(256,2).

#define W_OFF  0
#define XB_OFF 32768
#define FC_OFF 34816
#define LDS_SZ 36864

union HFu { bf16x8_t v; uint32_t u[4]; };

__device__ __forceinline__ void lstm_step(
    uint32_t xpack, uint32_t qmask,
    const uint8_t* __restrict__ base1,   // sLDS + lane*16   (W, FC frags)
    const uint8_t* __restrict__ base2,   // sLDS + XB_OFF + b*8
    HFu& HF0, HFu& HF1, float (&cs)[16])
{
    HFu ux;                              // B = x/bias: k'=0,1,2 on q==0 lanes
    ux.u[0] = xpack & qmask;
    ux.u[1] = 0x00003F80u & qmask;       // 1.0 bias slot
    ux.u[2] = 0u; ux.u[3] = 0u;

    uint32_t ph[4][2];

#define CHAIN(ss, gg)                                                        \
    { __builtin_amdgcn_sched_barrier(0);                                     \
      const int tt = (ss) * 4 + (gg);                                        \
      bf16x8_t w0 = *(const bf16x8_t*)(base1 + tt * 2048);                   \
      bf16x8_t w1 = *(const bf16x8_t*)(base1 + tt * 2048 + 1024);            \
      uint2 xd = *(const uint2*)(base2 + tt * 128);                          \
      HFu xw; xw.u[0] = xd.x & qmask; xw.u[1] = xd.y & qmask;                \
      xw.u[2] = 0u; xw.u[3] = 0u;                                            \
      acc = MFMA16(w0, HF0.v, ZERO4);                                        \
      acc = MFMA16(w1, HF1.v, acc);                                          \
      acc = MFMA16(xw.v, ux.v, acc); }

    #pragma unroll
    for (int s = 0; s < 4; ++s) {
        f32x4_t acc;
        float tg[4];

        // ---- gate g: tg = tanh-part ----
        CHAIN(s, 2)
        {
            float e0 = ex2(-acc[0]), e1 = ex2(-acc[1]);
            float e2 = ex2(-acc[2]), e3 = ex2(-acc[3]);
            float p0 = 1.f + e0, p1 = 1.f + e1, p2 = 1.f + e2, p3 = 1.f + e3;
            float ra = rcp_f(p0 * p1), rb = rcp_f(p2 * p3);
            tg[0] = (1.f - e0) * (ra * p1); tg[1] = (1.f - e1) * (ra * p0);
            tg[2] = (1.f - e2) * (rb * p3); tg[3] = (1.f - e3) * (rb * p2);
        }
        // ---- gate i: tg *= sigmoid(i) ----
        CHAIN(s, 0)
        {
            float e0 = ex2(-acc[0]), e1 = ex2(-acc[1]);
            float e2 = ex2(-acc[2]), e3 = ex2(-acc[3]);
            float p0 = 1.f + e0, p1 = 1.f + e1, p2 = 1.f + e2, p3 = 1.f + e3;
            float ra = rcp_f(p0 * p1), rb = rcp_f(p2 * p3);
            tg[0] *= (ra * p1); tg[1] *= (ra * p0);
            tg[2] *= (rb * p3); tg[3] *= (rb * p2);
        }
        // ---- gate f: c update; tg = tanh(c) ----
        CHAIN(s, 1)
        {
            float e0 = ex2(-acc[0]), e1 = ex2(-acc[1]);
            float e2 = ex2(-acc[2]), e3 = ex2(-acc[3]);
            float p0 = 1.f + e0, p1 = 1.f + e1, p2 = 1.f + e2, p3 = 1.f + e3;
            float ra = rcp_f(p0 * p1), rb = rcp_f(p2 * p3);
            float cn0 = (ra * p1) * cs[s * 4 + 0] + tg[0];
            float cn1 = (ra * p0) * cs[s * 4 + 1] + tg[1];
            float cn2 = (rb * p3) * cs[s * 4 + 2] + tg[2];
            float cn3 = (rb * p2) * cs[s * 4 + 3] + tg[3];
            cs[s * 4 + 0] = cn0; cs[s * 4 + 1] = cn1;
            cs[s * 4 + 2] = cn2; cs[s * 4 + 3] = cn3;
            float ec0 = ex2(-fminf(fmaxf(cn0 * LOG2E2, -43.f), 43.f));
            float ec1 = ex2(-fminf(fmaxf(cn1 * LOG2E2, -43.f), 43.f));
            float ec2 = ex2(-fminf(fmaxf(cn2 * LOG2E2, -43.f), 43.f));
            float ec3 = ex2(-fminf(fmaxf(cn3 * LOG2E2, -43.f), 43.f));
            float q0 = 1.f + ec0, q1 = 1.f + ec1, q2 = 1.f + ec2, q3 = 1.f + ec3;
            float Ca = rcp_f(q0 * q1), Cb = rcp_f(q2 * q3);
            tg[0] = (1.f - ec0) * (Ca * q1); tg[1] = (1.f - ec1) * (Ca * q0);
            tg[2] = (1.f - ec2) * (Cb * q3); tg[3] = (1.f - ec3) * (Cb * q2);
        }
        // ---- gate o: h = sigmoid(o) * tanh(c); pack (identity exchange) ----
        CHAIN(s, 3)
        {
            float e0 = ex2(-acc[0]), e1 = ex2(-acc[1]);
            float e2 = ex2(-acc[2]), e3 = ex2(-acc[3]);
            float p0 = 1.f + e0, p1 = 1.f + e1, p2 = 1.f + e2, p3 = 1.f + e3;
            float ra = rcp_f(p0 * p1), rb = rcp_f(p2 * p3);
            float h0 = tg[0] * (ra * p1), h1 = tg[1] * (ra * p0);
            float h2 = tg[2] * (rb * p3), h3 = tg[3] * (rb * p2);
            ph[s][0] = pk((__bf16)h0, (__bf16)h1);
            ph[s][1] = pk((__bf16)h2, (__bf16)h3);
        }
    }
#undef CHAIN
    HF0.u[0] = ph[0][0]; HF0.u[1] = ph[0][1];
    HF0.u[2] = ph[1][0]; HF0.u[3] = ph[1][1];
    HF1.u[0] = ph[2][0]; HF1.u[1] = ph[2][1];
    HF1.u[2] = ph[3][0]; HF1.u[3] = ph[3][1];
}

__global__ __launch_bounds__(256, 3) void seq2seq_lstm(
    const float* __restrict__ in_seq,
    const float* __restrict__ WihE, const float* __restrict__ WhhE,
    const float* __restrict__ bihE, const float* __restrict__ bhhE,
    const float* __restrict__ WihD, const float* __restrict__ WhhD,
    const float* __restrict__ bihD, const float* __restrict__ bhhD,
    const float* __restrict__ Wfc,  const float* __restrict__ bfc,
    float* __restrict__ out)
{
    __shared__ __align__(16) uint8_t sLDS[LDS_SZ];   // 36864 B

    const int tid  = threadIdx.x;
    const int lane = tid & 63;
    const int wave = tid >> 6;
    const int b    = lane & 15;          // batch within wave
    const int q    = lane >> 4;          // K-quarter / D-row group
    const uint32_t qmask = (q == 0) ? 0xFFFFFFFFu : 0u;

    auto stage_all = [&](const float* Whh, const float* Wih,
                         const float* bih, const float* bhh) {
        // W frags: 16 tiles x 2 chains x 64 lanes (A-row permuted by u(s,m))
        #pragma unroll 1
        for (int it = 0; it < 8; ++it) {
            int idx = it * 256 + tid;        // 0..2047
            int ln  = idx & 63;
            int tc  = idx >> 6;              // 0..31
            int c   = tc & 1;
            int tt  = tc >> 1;               // tile = s*4 + g
            int g   = tt & 3;
            int s   = tt >> 2;
            int n   = ln & 15, qq = ln >> 4;
            int a   = n >> 2,  r  = n & 3;
            int u   = 8 * a + 4 * (s & 1) + r + 32 * (s >> 1);
            int GU  = g * 64 + u;
            float sc = (g == 2) ? LOG2E2 : LOG2E;
            const float* src = Whh + GU * 64 + c * 32 + qq * 8;
            uint32_t wv[4];
            #pragma unroll
            for (int jj = 0; jj < 4; ++jj)
                wv[jj] = pk((__bf16)(sc * src[2 * jj]), (__bf16)(sc * src[2 * jj + 1]));
            uint32_t* d = (uint32_t*)(sLDS + tt * 2048 + c * 1024 + ln * 16);
            d[0] = wv[0]; d[1] = wv[1]; d[2] = wv[2]; d[3] = wv[3];
        }
        // XB frags: 16 tiles x 16 rows x 8B (k'=0,1,2 = Wih0,Wih1,bias)
        {
            int tt = tid >> 4, n = tid & 15; // tid covers all 256 slots
            int g  = tt & 3,  s = tt >> 2;
            int a  = n >> 2,  r = n & 3;
            int u  = 8 * a + 4 * (s & 1) + r + 32 * (s >> 1);
            int GU = g * 64 + u;
            float sc = (g == 2) ? LOG2E2 : LOG2E;
            uint2 d2;
            d2.x = pk((__bf16)(sc * Wih[GU * 2 + 0]), (__bf16)(sc * Wih[GU * 2 + 1]));
            d2.y = pk((__bf16)(sc * (bih[GU] + bhh[GU])), (__bf16)0.0f);
            *(uint2*)(sLDS + XB_OFF + tt * 128 + n * 8) = d2;
        }
    };

    stage_all(WhhE, WihE, bihE, bhhE);
    __syncthreads();

    const int rowBase = blockIdx.x * (NW * BPW) + wave * BPW;
    const uint8_t* base1 = sLDS + lane * 16;
    const uint8_t* base2 = sLDS + XB_OFF + b * 8;

    HFu HF0, HF1;
    HF0.u[0] = HF0.u[1] = HF0.u[2] = HF0.u[3] = 0u;
    HF1.u[0] = HF1.u[1] = HF1.u[2] = HF1.u[3] = 0u;
    float cs[16];
    #pragma unroll
    for (int j = 0; j < 16; ++j) cs[j] = 0.f;

    // ================= encoder: barrier-free, x lane-local =================
    const float* gsrc = in_seq + (size_t)(rowBase + b) * (T_IN * 2);
    float4 pf = *(const float4*)gsrc;                 // steps t, t+1
    #pragma unroll 1
    for (int t = 0; t < T_IN; ++t) {
        uint32_t xa = (t & 1) ? pk((__bf16)pf.z, (__bf16)pf.w)
                              : pk((__bf16)pf.x, (__bf16)pf.y);
        if ((t & 1) && t < T_IN - 1)
            pf = *(const float4*)(gsrc + (t + 1) * 2);
        lstm_step(xa, qmask, base1, base2, HF0, HF1, cs);
    }

    // ============ switch to decoder weights ============
    __syncthreads();
    stage_all(WhhD, WihD, bihD, bhhD);
    if (tid < 128) {                      // FC A-frags: rows 0,1 = Wfc, rest 0
        int c = tid >> 6, ln = tid & 63;
        int m = ln & 15, qq = ln >> 4;
        uint32_t w[4];
        #pragma unroll
        for (int jj = 0; jj < 4; ++jj) {
            int k = c * 32 + qq * 8 + 2 * jj;
            w[jj] = (m < 2) ? pk((__bf16)Wfc[m * 64 + k], (__bf16)Wfc[m * 64 + k + 1])
                            : 0u;
        }
        uint32_t* d = (uint32_t*)(sLDS + FC_OFF + c * 1024 + ln * 16);
        d[0] = w[0]; d[1] = w[1]; d[2] = w[2]; d[3] = w[3];
    }
    __syncthreads();

    uint32_t xpack = pk((__bf16)pf.z, (__bf16)pf.w);  // input_seq[:, -1]
    const float nb0 = -LOG2E * bfc[0], nb1 = -LOG2E * bfc[1];

    // ================= decoder: barrier-free =================
    #pragma unroll 1
    for (int td = 0; td < T_OUT; ++td) {
        lstm_step(xpack, qmask, base1, base2, HF0, HF1, cs);
        // FC via 2 MFMAs on the NEW h frags; rows 0,1 live on q==0 lanes
        __builtin_amdgcn_sched_barrier(0);
        f32x4_t pc = MFMA16(*(const bf16x8_t*)(base1 + FC_OFF),        HF0.v, ZERO4);
        pc = MFMA16(*(const bf16x8_t*)(base1 + FC_OFF + 1024), HF1.v, pc);
        if (q == 0) {                                 // lane owns batch b
            float p0 = rcp_f(1.f + ex2(__builtin_fmaf(-LOG2E, pc[0], nb0)));
            float p1 = rcp_f(1.f + ex2(__builtin_fmaf(-LOG2E, pc[1], nb1)));
            *(float2*)(out + ((size_t)(rowBase + b) * T_OUT + td) * 2)
                = make_float2(p0, p1);
            xpack = pk((__bf16)p0, (__bf16)p1);       // in-register feedback
        }
        // q>0 lanes keep stale xpack: masked by qmask, never consumed
    }
}

extern "C" void kernel_launch(void* const* d_in, const int* in_sizes, int n_in,
                              void* d_out, int out_size, void* d_ws, size_t ws_size,
                              hipStream_t stream) {
    const float* in_seq = (const float*)d_in[0];
    const float* WihE = (const float*)d_in[1];
    const float* WhhE = (const float*)d_in[2];
    const float* bihE = (const float*)d_in[3];
    const float* bhhE = (const float*)d_in[4];
    const float* WihD = (const float*)d_in[5];
    const float* WhhD = (const float*)d_in[6];
    const float* bihD = (const float*)d_in[7];
    const float* bhhD = (const float*)d_in[8];
    const float* Wfc  = (const float*)d_in[9];
    const float* bfcp = (const float*)d_in[10];
    float* out = (float*)d_out;

    const int B = in_sizes[0] / (T_IN * 2);          // 131072
    dim3 grid(B / (NW * BPW)), block(NW * 64);       // 64 rows/block, 256 thr
    hipLaunchKernelGGL(seq2seq_lstm, grid, block, 0, stream,
                       in_seq, WihE, WhhE, bihE, bhhE,
                       WihD, WhhD, bihD, bhhD, Wfc, bfcp, out);
}